// Round 13
// baseline (356.851 us; speedup 1.0000x reference)
//
#include <hip/hip_runtime.h>
#include <hip/hip_bf16.h>

#define NPAT 50000
#define NCON 20000
#define NN   70000
#define EE   800000
#define H    128
#define HH   (H * H)

#define NCON_AL  20032                 // concepts padded to 64-alignment
#define SEGN     (NCON_AL + NPAT)      // 70032 segment ids
#define NBUCK    1095                  // ceil(SEGN/64)
#define RELSPLIT_B 313                 // buckets [0,313) = concept dsts (rel0)
#define BUCKCAP  5120                  // pairs capacity per bucket (max fill ~2900)
#define SUBS     16                    // sub-regions per bucket (reservation slots)
#define SUBCAP   (BUCKCAP / SUBS)      // 320 (max fill ~236)
#define BPE      4096                  // edges per binpack block
#define NBB      ((2 * EE + BPE - 1) / BPE)   // 391
#define CAP      4096                  // sorted-src capacity per bucket (max ~2900)

#define BM 128
#define BK 8
#define PB_T 391                       // patient row tiles
#define CB_T 157                       // concept row tiles
#define SLAB2 (128 * 64)               // shorts per 64-k slab
#define MATW (2 * SLAB2)               // shorts per prepped weight matrix
#define NSEG64 (NBUCK * 64)            // 70080 dcnt slots (covers tail bucket)
#define ZG ((NBUCK * SUBS + 255) / 256)       // 69 gcur-zero blocks
#define ZD ((NSEG64 + 255) / 256)             // 274 dcnt-zero blocks

typedef __attribute__((ext_vector_type(8))) short bf16x8;
typedef __attribute__((ext_vector_type(4))) float f32x4;

__device__ inline unsigned short f2bf(float f) {
    unsigned u = __float_as_uint(f);
    unsigned r = (u + 0x7FFFu + ((u >> 16) & 1u)) >> 16;
    return (unsigned short)r;
}
__device__ inline float bf2f_lo(unsigned v) { return __uint_as_float(v << 16); }
__device__ inline float bf2f_hi(unsigned v) { return __uint_as_float(v & 0xFFFF0000u); }

// ============ prep: weights -> bf16 64-k slabs; tail blocks zero gcur + dcnt ======
__global__ __launch_bounds__(256) void prep_weights_kernel(
        const float* __restrict__ W_root, const float* __restrict__ W_rel,
        unsigned short* __restrict__ prepW, int* __restrict__ gcur,
        int* __restrict__ dcnt) {
    __shared__ unsigned short sT[64][130];
    int t = threadIdx.x, blk = blockIdx.x;
    if (blk >= 12 + ZG) {                        // dcnt zeroing role
        int i = (blk - 12 - ZG) * 256 + t;
        if (i < NSEG64) dcnt[i] = 0;
        return;
    }
    if (blk >= 12) {                             // gcur zeroing role
        int i = (blk - 12) * 256 + t;
        if (i < NBUCK * SUBS) gcur[i] = 0;
        return;
    }
    int m = blk >> 1, kt2 = blk & 1;
    const float* src = (m % 3 == 0)
        ? (W_root + (size_t)(m / 3) * HH)
        : (W_rel + (size_t)((m / 3) * 2 + (m % 3) - 1) * HH);
    int k0 = kt2 * 64;
    int row = t >> 2, col0 = (t & 3) * 32;       // 64 k-rows, 32 cols/thread
    const float* sp = src + (size_t)(k0 + row) * H + col0;
#pragma unroll
    for (int i = 0; i < 32; i++) sT[row][col0 + i] = f2bf(sp[i]);
    __syncthreads();
    int col = t >> 1, koff = (t & 1) * 32;       // transpose out of LDS
    unsigned short* op = prepW + (size_t)m * MATW + kt2 * SLAB2 + col * 64 + koff;
    unsigned short tmp[32] __attribute__((aligned(16)));
#pragma unroll
    for (int i = 0; i < 32; i++) tmp[i] = sT[koff + i][col];
    *(uint4*)&op[0]  = *(uint4*)&tmp[0];
    *(uint4*)&op[8]  = *(uint4*)&tmp[8];
    *(uint4*)&op[16] = *(uint4*)&tmp[16];
    *(uint4*)&op[24] = *(uint4*)&tmp[24];
}

// ============ binpack: 512 thr, LDS counting sort by bucket, run-reserve, write ====
// Also accumulates per-SEGMENT degree dcnt[seg] (global, no-return atomics) so
// the gather_build can skip its counting pass entirely.
__global__ __launch_bounds__(512) void binpack_kernel(
        const int* __restrict__ dst_pc, const int* __restrict__ src_pc,
        const int* __restrict__ dst_cp, const int* __restrict__ src_cp,
        int* __restrict__ gcur, unsigned* __restrict__ pairs,
        int* __restrict__ dcnt) {
    __shared__ unsigned sval[BPE];           // 16 KB
    __shared__ unsigned short sbkt[BPE];     // 8 KB
    __shared__ int cnt[NBUCK];               // 4.4 KB (then local cursor)
    __shared__ int delta[NBUCK];             // 4.4 KB
    __shared__ int wtot[8];
    int t = threadIdx.x, blk = blockIdx.x;
    int base = blk * BPE;
    int n = min(BPE, 2 * EE - base);

    for (int i = t; i < NBUCK; i += 512) cnt[i] = 0;
    __syncthreads();

    unsigned pay[8];
    int bkt[8];
#pragma unroll
    for (int q = 0; q < 8; q++) {
        int li = q * 512 + t;
        bkt[q] = -1;
        if (li < n) {
            int i = base + li;
            int seg, src;
            if (i < EE) { seg = dst_pc[i];                src = src_pc[i]; }
            else        { seg = NCON_AL + dst_cp[i - EE]; src = src_cp[i - EE]; }
            int b = seg >> 6;
            pay[q] = (unsigned)src | ((unsigned)(seg & 63) << 16);
            bkt[q] = b;
            atomicAdd(&cnt[b], 1);
            atomicAdd(&dcnt[seg], 1);        // per-seg degree for gather_build
        }
    }
    __syncthreads();

    const int PER = (NBUCK + 511) / 512;   // 3
    int beg = t * PER;
    int s = 0;
#pragma unroll
    for (int k = 0; k < PER; k++) { int i = beg + k; if (i < NBUCK) s += cnt[i]; }
    // per-wave inclusive scan + cross-wave combine (2 barriers)
    int lane = t & 63, w8 = t >> 6;
    int incl = s;
#pragma unroll
    for (int o = 1; o < 64; o <<= 1) {
        int u = __shfl_up(incl, o);
        if (lane >= o) incl += u;
    }
    if (lane == 63) wtot[w8] = incl;
    __syncthreads();
    if (t == 0) {
        int r0 = 0;
#pragma unroll
        for (int k = 0; k < 8; k++) { int tmp = wtot[k]; wtot[k] = r0; r0 += tmp; }
    }
    __syncthreads();
    int run = incl - s + wtot[w8];

    int sub = blk & (SUBS - 1);
    int prefk[PER];
#pragma unroll
    for (int k = 0; k < PER; k++) {
        int i = beg + k;
        if (i < NBUCK) {
            prefk[k] = run;
            int c = cnt[i];
            if (c > 0) {
                int gb = atomicAdd(&gcur[i * SUBS + sub], c);   // relative cursor
                delta[i] = (i * BUCKCAP + sub * SUBCAP + gb) - run;
            }
            run += c;
        }
    }
    __syncthreads();
#pragma unroll
    for (int k = 0; k < PER; k++) { int i = beg + k; if (i < NBUCK) cnt[i] = prefk[k]; }
    __syncthreads();

#pragma unroll
    for (int q = 0; q < 8; q++) {
        if (bkt[q] >= 0) {
            int b = bkt[q];
            int pos = atomicAdd(&cnt[b], 1);
            sval[pos] = pay[q];
            sbkt[pos] = (unsigned short)b;
        }
    }
    __syncthreads();
    for (int i = t; i < n; i += 512)
        pairs[delta[sbkt[i]] + i] = sval[i];
}

// ============ proj GEMM (fp32 VALU, 256 thr, r2-proven) ============
struct GemmJob {
    const float* A1;
    const float* B1;
    const float* bias; unsigned short* Cbf;
    int lda1, K1, M;
};

__global__ void gemm_dual_kernel(GemmJob j0, GemmJob j1, int nb0) {
    __shared__ float sA[BK][BM];
    __shared__ float sB[BK][H];
    bool first = (int)blockIdx.x < nb0;
    GemmJob j = first ? j0 : j1;
    int bm = (first ? blockIdx.x : blockIdx.x - nb0) * BM;
    int tid = threadIdx.x;
    int am = tid >> 1;
    int ak = (tid & 1) * 4;
    int bk = tid >> 5;
    int bn = (tid & 31) * 4;
    int ty = tid >> 4;
    int tx = tid & 15;
    float acc[8][8] = {};
    for (int k0 = 0; k0 < j.K1; k0 += BK) {
        int gm = bm + am; if (gm >= j.M) gm = j.M - 1;
        float4 av = *(const float4*)&j.A1[(size_t)gm * j.lda1 + k0 + ak];
        float4 bv = *(const float4*)&j.B1[(size_t)(k0 + bk) * H + bn];
        __syncthreads();
        sA[ak + 0][am] = av.x; sA[ak + 1][am] = av.y;
        sA[ak + 2][am] = av.z; sA[ak + 3][am] = av.w;
        *(float4*)&sB[bk][bn] = bv;
        __syncthreads();
#pragma unroll
        for (int k = 0; k < BK; k++) {
            float a[8], bb[8];
            *(float4*)&a[0] = *(const float4*)&sA[k][ty * 8];
            *(float4*)&a[4] = *(const float4*)&sA[k][ty * 8 + 4];
            *(float4*)&bb[0] = *(const float4*)&sB[k][tx * 4];
            *(float4*)&bb[4] = *(const float4*)&sB[k][64 + tx * 4];
#pragma unroll
            for (int i = 0; i < 8; i++)
#pragma unroll
                for (int jj = 0; jj < 8; jj++)
                    acc[i][jj] += a[i] * bb[jj];
        }
    }
    float bcol[8];
    *(float4*)&bcol[0] = *(const float4*)&j.bias[tx * 4];
    *(float4*)&bcol[4] = *(const float4*)&j.bias[64 + tx * 4];
#pragma unroll
    for (int i = 0; i < 8; i++) {
        int gr = bm + ty * 8 + i;
        if (gr < j.M) {
#pragma unroll
            for (int q = 0; q < 8; q++) {
                float v = acc[i][q] + bcol[q];
                int gc = (q < 4) ? (tx * 4 + q) : (64 + tx * 4 + q - 4);
                j.Cbf[(size_t)gr * H + gc] = f2bf(v);
            }
        }
    }
}

// ============ shared gather body (reads soff/ssrc from LDS) ============
#define ACC8(a0, a1, v) \
    a0.x += bf2f_lo((v).x); a0.y += bf2f_hi((v).x); \
    a0.z += bf2f_lo((v).y); a0.w += bf2f_hi((v).y); \
    a1.x += bf2f_lo((v).z); a1.y += bf2f_hi((v).z); \
    a1.z += bf2f_lo((v).w); a1.w += bf2f_hi((v).w);

__device__ inline void gather_body(
        int t, int b, const int* soff, const unsigned short* ssrc,
        const unsigned short* __restrict__ xbf, unsigned short* __restrict__ aggn) {
    int wv = t >> 6, lane = t & 63;
    int g = lane >> 4;          // edge slot 0..3
    int q = lane & 15;          // uint4 index within row (16 B granule)
    int rowbase = (b < RELSPLIT_B) ? 0 : NPAT;
    int seglim  = (b < RELSPLIT_B) ? NCON : SEGN;
    const uint4* xw4 = (const uint4*)xbf;   // 16 x uint4 per row
    for (int i = 0; i < 8; i++) {
        int d = wv * 8 + i;
        int seg = b * 64 + d;
        if (seg >= seglim) continue;
        int beg = soff[d], end = soff[d + 1];
        float4 aA0 = {0.f, 0.f, 0.f, 0.f}, aA1 = {0.f, 0.f, 0.f, 0.f};
        float4 aB0 = {0.f, 0.f, 0.f, 0.f}, aB1 = {0.f, 0.f, 0.f, 0.f};
        int j = beg;
        for (; j + 7 < end; j += 8) {  // 8 edges via 2 independent uint4/lane
            int sA = ssrc[j + g];
            int sB = ssrc[j + 4 + g];
            uint4 vA = xw4[(size_t)(rowbase + sA) * 16 + q];
            uint4 vB = xw4[(size_t)(rowbase + sB) * 16 + q];
            ACC8(aA0, aA1, vA);
            ACC8(aB0, aB1, vB);
        }
        for (; j < end; j += 4) {      // tail: masked rounds of up to 4 edges
            if (g < end - j) {
                int s0 = ssrc[j + g];
                uint4 v = xw4[(size_t)(rowbase + s0) * 16 + q];
                ACC8(aA0, aA1, v);
            }
        }
        aA0.x += aB0.x; aA0.y += aB0.y; aA0.z += aB0.z; aA0.w += aB0.w;
        aA1.x += aB1.x; aA1.y += aB1.y; aA1.z += aB1.z; aA1.w += aB1.w;
        float r0 = aA0.x, r1 = aA0.y, r2 = aA0.z, r3 = aA0.w;
        float r4 = aA1.x, r5 = aA1.y, r6 = aA1.z, r7 = aA1.w;
        // reduce across the 4 edge-slots (lane bits 4 and 5)
        r0 += __shfl_xor(r0, 16); r1 += __shfl_xor(r1, 16);
        r2 += __shfl_xor(r2, 16); r3 += __shfl_xor(r3, 16);
        r4 += __shfl_xor(r4, 16); r5 += __shfl_xor(r5, 16);
        r6 += __shfl_xor(r6, 16); r7 += __shfl_xor(r7, 16);
        r0 += __shfl_xor(r0, 32); r1 += __shfl_xor(r1, 32);
        r2 += __shfl_xor(r2, 32); r3 += __shfl_xor(r3, 32);
        r4 += __shfl_xor(r4, 32); r5 += __shfl_xor(r5, 32);
        r6 += __shfl_xor(r6, 32); r7 += __shfl_xor(r7, 32);
        if (g == 0) {
            float inv = 1.0f / (float)max(end - beg, 1);
            uint4 o;
            o.x = (unsigned)f2bf(r0 * inv) | ((unsigned)f2bf(r1 * inv) << 16);
            o.y = (unsigned)f2bf(r2 * inv) | ((unsigned)f2bf(r3 * inv) << 16);
            o.z = (unsigned)f2bf(r4 * inv) | ((unsigned)f2bf(r5 * inv) << 16);
            o.w = (unsigned)f2bf(r6 * inv) | ((unsigned)f2bf(r7 * inv) << 16);
            *(uint4*)&aggn[(size_t)seg * H + 8 * q] = o;  // zero-deg segs write 0 (required)
        }
    }
}

// ============ layer-0: scan dcnt, place, dump for l1, gather from LDS ============
// Pass A (counting sweep over pairs) eliminated: binpack pre-computed dcnt[seg].
__global__ __launch_bounds__(512) void gather_build_kernel(
        const unsigned short* __restrict__ xbf,
        unsigned* __restrict__ pairs, const int* __restrict__ gcur,
        const int* __restrict__ dcnt,
        int* __restrict__ soffg, unsigned short* __restrict__ aggn) {
    __shared__ int soff[65];
    __shared__ int scur[64];
    __shared__ unsigned short ssrc[CAP];
    int t = threadIdx.x, b = blockIdx.x;
    if (t < 64) {  // wave 0: exclusive scan over precomputed degrees
        int v = dcnt[b * 64 + t];
        int s = v;
#pragma unroll
        for (int o = 1; o < 64; o <<= 1) {
            int u = __shfl_up(s, o);
            if (t >= o) s += u;
        }
        soff[t + 1] = s;
        if (t == 0) soff[0] = 0;
        scur[t] = s - v;
    }
    __syncthreads();
    // place srcs per-dst-contiguous
    for (int s = 0; s < SUBS; s++) {
        int rbase = b * BUCKCAP + s * SUBCAP;
        int rcnt = gcur[b * SUBS + s];
        for (int i = t; i < rcnt; i += 512) {
            unsigned p = pairs[rbase + i];
            int pos = atomicAdd(&scur[p >> 16], 1);
            ssrc[pos] = (unsigned short)(p & 0xFFFF);
        }
    }
    __syncthreads();
    // dump for layer 1 (fire-and-forget; overlaps the gather below)
    if (t < 65) soffg[b * 65 + t] = soff[t];
    int tot = soff[64];
    unsigned* sg = (unsigned*)(((unsigned short*)pairs) + (size_t)b * BUCKCAP * 2);
    const unsigned* sl = (const unsigned*)ssrc;
    for (int i = t; i < ((tot + 1) >> 1); i += 512) sg[i] = sl[i];
    // gather directly from the LDS csr just built
    gather_body(t, b, soff, ssrc, xbf, aggn);
}

// ============ layer-1 gather: load dumped CSR, then gather (r2-proven) ============
__global__ __launch_bounds__(512) void gather_kernel(
        const unsigned short* __restrict__ xbf,
        const unsigned short* __restrict__ ssrcg,
        const int* __restrict__ soffg,
        unsigned short* __restrict__ aggn) {
    __shared__ int soff[65];
    __shared__ unsigned short ssrc[CAP];
    int t = threadIdx.x, b = blockIdx.x;
    if (t < 65) soff[t] = soffg[b * 65 + t];
    __syncthreads();
    int tot = soff[64];
    const unsigned* sg = (const unsigned*)(ssrcg + (size_t)b * BUCKCAP * 2);
    unsigned* sl = (unsigned*)ssrc;
    for (int i = t; i < ((tot + 1) >> 1); i += 512) sl[i] = sg[i];
    __syncthreads();
    gather_body(t, b, soff, ssrc, xbf, aggn);
}

// ============ layer GEMM (bf16 MFMA, BK=64, r11): C = [A1|A2]@[BT1;BT2]+bias, relu
struct MJob {
    const unsigned short* A1;  // [M][H] bf16
    const unsigned short* A2;  // [M][H] bf16
    const unsigned short* BT1; // [2][128][64] bf16 slabs (k 0..127)
    const unsigned short* BT2; // [2][128][64] bf16 slabs (k 128..255)
    const float* bias;
    float* C;                  // fp32 or null
    unsigned short* Cbf;       // bf16 or null
    int M;
};

__global__ __launch_bounds__(256) void gemm_mfma_kernel(MJob j0, MJob j1, int nb0) {
    __shared__ unsigned short sA[128][72];   // [row][k] pad 64->72 (144B = 9x16)
    __shared__ unsigned short sBT[128][72];  // [col][k]
    bool first = (int)blockIdx.x < nb0;
    MJob J = first ? j0 : j1;
    int bm = (first ? (int)blockIdx.x : (int)blockIdx.x - nb0) * 128;
    int tid = threadIdx.x;
    int wv = tid >> 6, lane = tid & 63;
    int wr = wv >> 1, wc = wv & 1;
    int m16 = lane & 15, kg = lane >> 4;

    f32x4 acc[4][4];
#pragma unroll
    for (int a = 0; a < 4; a++)
#pragma unroll
        for (int c = 0; c < 4; c++) acc[a][c] = (f32x4){0.f, 0.f, 0.f, 0.f};

    int ar = tid >> 1, ah = (tid & 1) * 32;      // A: row, 32-short (64B) half
    int gmA = bm + ar; if (gmA >= J.M) gmA = J.M - 1;
    int bcol = tid >> 1, bko = (tid & 1) * 32;   // B: col, 32-short k-half

#pragma unroll
    for (int kt = 0; kt < 4; kt++) {
        int k0 = kt * 64;
        const unsigned short* asrc = (kt < 2)
            ? (J.A1 + (size_t)gmA * H + k0 + ah)
            : (J.A2 + (size_t)gmA * H + (k0 - 128) + ah);
        const uint4* a4 = (const uint4*)asrc;
        uint4 av0 = a4[0], av1 = a4[1], av2 = a4[2], av3 = a4[3];
        const unsigned short* slab = (kt < 2) ? (J.BT1 + kt * SLAB2)
                                              : (J.BT2 + (kt - 2) * SLAB2);
        const uint4* b4 = (const uint4*)(slab + bcol * 64 + bko);
        uint4 bv0 = b4[0], bv1 = b4[1], bv2 = b4[2], bv3 = b4[3];
        __syncthreads();
        { uint4* d4 = (uint4*)&sA[ar][ah];
          d4[0] = av0; d4[1] = av1; d4[2] = av2; d4[3] = av3; }
        { uint4* d4 = (uint4*)&sBT[bcol][bko];
          d4[0] = bv0; d4[1] = bv1; d4[2] = bv2; d4[3] = bv3; }
        __syncthreads();
#pragma unroll
        for (int kk = 0; kk < 2; kk++) {
            bf16x8 af[4], bfg[4];
#pragma unroll
            for (int mt = 0; mt < 4; mt++)
                af[mt] = *(bf16x8*)&sA[wr * 64 + mt * 16 + m16][kk * 32 + kg * 8];
#pragma unroll
            for (int nt = 0; nt < 4; nt++)
                bfg[nt] = *(bf16x8*)&sBT[wc * 64 + nt * 16 + m16][kk * 32 + kg * 8];
#pragma unroll
            for (int mt = 0; mt < 4; mt++)
#pragma unroll
                for (int nt = 0; nt < 4; nt++)
                    acc[mt][nt] = __builtin_amdgcn_mfma_f32_16x16x32_bf16(
                        af[mt], bfg[nt], acc[mt][nt], 0, 0, 0);
        }
    }
    float bv[4];
#pragma unroll
    for (int nt = 0; nt < 4; nt++) bv[nt] = J.bias[wc * 64 + nt * 16 + m16];
#pragma unroll
    for (int mt = 0; mt < 4; mt++) {
        int gr0 = bm + wr * 64 + mt * 16 + kg * 4;
#pragma unroll
        for (int r = 0; r < 4; r++) {
            int gr = gr0 + r;
            if (gr < J.M) {
#pragma unroll
                for (int nt = 0; nt < 4; nt++) {
                    int gc = wc * 64 + nt * 16 + m16;
                    float v = fmaxf(acc[mt][nt][r] + bv[nt], 0.f);
                    if (J.C)   J.C[(size_t)gr * H + gc] = v;
                    if (J.Cbf) J.Cbf[(size_t)gr * H + gc] = f2bf(v);
                }
            }
        }
    }
}

// ============ launch ============

static inline size_t align256(size_t x) { return (x + 255) & ~(size_t)255; }

extern "C" void kernel_launch(void* const* d_in, const int* in_sizes, int n_in,
                              void* d_out, int out_size, void* d_ws, size_t ws_size,
                              hipStream_t stream) {
    const float* x_patient = (const float*)d_in[0];
    const float* x_concept = (const float*)d_in[1];
    const float* W_p       = (const float*)d_in[2];
    const float* b_p       = (const float*)d_in[3];
    const float* W_c       = (const float*)d_in[4];
    const float* b_c       = (const float*)d_in[5];
    const float* W_root    = (const float*)d_in[6];
    const float* b_root    = (const float*)d_in[7];
    const float* W_rel     = (const float*)d_in[8];
    const int*   src_pc    = (const int*)d_in[9];
    const int*   dst_pc    = (const int*)d_in[10];
    const int*   src_cp    = (const int*)d_in[11];
    const int*   dst_cp    = (const int*)d_in[12];
    float* out = (float*)d_out;

    // every carve 256B-aligned (r8 lesson: unaligned carve -> misaligned uint4
    // accesses -> GPU fault)
    char* w = (char*)d_ws;
    unsigned short* xbf  = (unsigned short*)w; w += align256((size_t)NN * H * 2);
    unsigned short* aggn = (unsigned short*)w; w += align256((size_t)SEGN * H * 2);
    int* gcur = (int*)w;            w += align256((size_t)NBUCK * SUBS * 4);
    unsigned* pairs = (unsigned*)w; w += align256((size_t)NBUCK * BUCKCAP * 4);
    int* soffg = (int*)w;           w += align256((size_t)NBUCK * 65 * 4);
    unsigned short* prepW = (unsigned short*)w; w += align256((size_t)6 * MATW * 2);
    int* dcnt = (int*)w;            w += align256((size_t)NSEG64 * 4);

    prep_weights_kernel<<<12 + ZG + ZD, 256, 0, stream>>>(W_root, W_rel, prepW,
                                                          gcur, dcnt);
    binpack_kernel<<<NBB, 512, 0, stream>>>(dst_pc, src_pc, dst_cp, src_cp,
                                            gcur, pairs, dcnt);
    const unsigned short* ssrcg = (const unsigned short*)pairs;  // l0 dumps here

    // projections -> xbf
    {
        GemmJob jp = { x_patient, W_p, b_p, xbf, 64, 64, NPAT };
        GemmJob jc = { x_concept, W_c, b_c, xbf + (size_t)NPAT * H, 128, 128, NCON };
        gemm_dual_kernel<<<PB_T + CB_T, 256, 0, stream>>>(jp, jc, PB_T);
    }

    for (int l = 0; l < 2; l++) {
        if (l == 0)
            gather_build_kernel<<<NBUCK, 512, 0, stream>>>(xbf, pairs, gcur, dcnt,
                                                           soffg, aggn);
        else
            gather_kernel<<<NBUCK, 512, 0, stream>>>(xbf, ssrcg, soffg, aggn);
        const unsigned short* BTroot = prepW + (size_t)(3 * l + 0) * MATW;
        const unsigned short* BTrel0 = prepW + (size_t)(3 * l + 1) * MATW;
        const unsigned short* BTrel1 = prepW + (size_t)(3 * l + 2) * MATW;
        const float* br = b_root + (size_t)l * H;
        float* cp = (l == 1) ? out : nullptr;
        float* cc = (l == 1) ? out + (size_t)NPAT * H : nullptr;
        unsigned short* bp = (l == 0) ? xbf : nullptr;                       // in-place ok
        unsigned short* bc = (l == 0) ? xbf + (size_t)NPAT * H : nullptr;
        MJob jp = { xbf, aggn + (size_t)NCON_AL * H, BTroot, BTrel1, br,
                    cp, bp, NPAT };
        MJob jc = { xbf + (size_t)NPAT * H, aggn, BTroot, BTrel0, br,
                    cc, bc, NCON };
        gemm_mfma_kernel<<<PB_T + CB_T, 256, 0, stream>>>(jp, jc, PB_T);
    }
}

// Round 14
// 300.726 us; speedup vs baseline: 1.1866x; 1.1866x over previous
//
#include <hip/hip_runtime.h>
#include <hip/hip_bf16.h>

#define NPAT 50000
#define NCON 20000
#define NN   70000
#define EE   800000
#define H    128
#define HH   (H * H)

#define NCON_AL  20032                 // concepts padded to 64-alignment
#define SEGN     (NCON_AL + NPAT)      // 70032 segment ids
#define NBUCK    1095                  // ceil(SEGN/64)
#define RELSPLIT_B 313                 // buckets [0,313) = concept dsts (rel0)
#define BUCKCAP  5120                  // pairs capacity per bucket (max fill ~2900)
#define SUBS     16                    // sub-regions per bucket (reservation slots)
#define SUBCAP   (BUCKCAP / SUBS)      // 320 (max fill ~236)
#define BPE      4096                  // edges per binpack block
#define NBB      ((2 * EE + BPE - 1) / BPE)   // 391
#define CAP      4096                  // sorted-src capacity per bucket (max ~2900)

#define BM 128
#define BK 8
#define PB_T 391                       // patient row tiles
#define CB_T 157                       // concept row tiles
#define SLAB2 (128 * 64)               // shorts per 64-k slab
#define MATW (2 * SLAB2)               // shorts per prepped weight matrix
#define ZBLKS ((NBUCK * SUBS + 255) / 256)    // 69 gcur-zeroing blocks

typedef __attribute__((ext_vector_type(8))) short bf16x8;
typedef __attribute__((ext_vector_type(4))) float f32x4;

__device__ inline unsigned short f2bf(float f) {
    unsigned u = __float_as_uint(f);
    unsigned r = (u + 0x7FFFu + ((u >> 16) & 1u)) >> 16;
    return (unsigned short)r;
}
__device__ inline float bf2f_lo(unsigned v) { return __uint_as_float(v << 16); }
__device__ inline float bf2f_hi(unsigned v) { return __uint_as_float(v & 0xFFFF0000u); }

// ============ prep: weights -> bf16 64-k slabs; blocks >= 12 zero gcur ============
__global__ __launch_bounds__(256) void prep_weights_kernel(
        const float* __restrict__ W_root, const float* __restrict__ W_rel,
        unsigned short* __restrict__ prepW, int* __restrict__ gcur) {
    __shared__ unsigned short sT[64][130];
    int t = threadIdx.x, blk = blockIdx.x;
    if (blk >= 12) {                             // gcur zeroing role
        int i = (blk - 12) * 256 + t;
        if (i < NBUCK * SUBS) gcur[i] = 0;
        return;
    }
    int m = blk >> 1, kt2 = blk & 1;
    const float* src = (m % 3 == 0)
        ? (W_root + (size_t)(m / 3) * HH)
        : (W_rel + (size_t)((m / 3) * 2 + (m % 3) - 1) * HH);
    int k0 = kt2 * 64;
    int row = t >> 2, col0 = (t & 3) * 32;       // 64 k-rows, 32 cols/thread
    const float* sp = src + (size_t)(k0 + row) * H + col0;
#pragma unroll
    for (int i = 0; i < 32; i++) sT[row][col0 + i] = f2bf(sp[i]);
    __syncthreads();
    int col = t >> 1, koff = (t & 1) * 32;       // transpose out of LDS
    unsigned short* op = prepW + (size_t)m * MATW + kt2 * SLAB2 + col * 64 + koff;
    unsigned short tmp[32] __attribute__((aligned(16)));
#pragma unroll
    for (int i = 0; i < 32; i++) tmp[i] = sT[koff + i][col];
    *(uint4*)&op[0]  = *(uint4*)&tmp[0];
    *(uint4*)&op[8]  = *(uint4*)&tmp[8];
    *(uint4*)&op[16] = *(uint4*)&tmp[16];
    *(uint4*)&op[24] = *(uint4*)&tmp[24];
}

// ============ binpack: 512 thr, LDS counting sort by bucket, run-reserve, write ====
__global__ __launch_bounds__(512) void binpack_kernel(
        const int* __restrict__ dst_pc, const int* __restrict__ src_pc,
        const int* __restrict__ dst_cp, const int* __restrict__ src_cp,
        int* __restrict__ gcur, unsigned* __restrict__ pairs) {
    __shared__ unsigned sval[BPE];           // 16 KB
    __shared__ unsigned short sbkt[BPE];     // 8 KB
    __shared__ int cnt[NBUCK];               // 4.4 KB (then local cursor)
    __shared__ int delta[NBUCK];             // 4.4 KB
    __shared__ int wtot[8];
    int t = threadIdx.x, blk = blockIdx.x;
    int base = blk * BPE;
    int n = min(BPE, 2 * EE - base);

    for (int i = t; i < NBUCK; i += 512) cnt[i] = 0;
    __syncthreads();

    unsigned pay[8];
    int bkt[8];
#pragma unroll
    for (int q = 0; q < 8; q++) {
        int li = q * 512 + t;
        bkt[q] = -1;
        if (li < n) {
            int i = base + li;
            int seg, src;
            if (i < EE) { seg = dst_pc[i];                src = src_pc[i]; }
            else        { seg = NCON_AL + dst_cp[i - EE]; src = src_cp[i - EE]; }
            int b = seg >> 6;
            pay[q] = (unsigned)src | ((unsigned)(seg & 63) << 16);
            bkt[q] = b;
            atomicAdd(&cnt[b], 1);
        }
    }
    __syncthreads();

    const int PER = (NBUCK + 511) / 512;   // 3
    int beg = t * PER;
    int s = 0;
#pragma unroll
    for (int k = 0; k < PER; k++) { int i = beg + k; if (i < NBUCK) s += cnt[i]; }
    // per-wave inclusive scan + cross-wave combine (2 barriers)
    int lane = t & 63, w8 = t >> 6;
    int incl = s;
#pragma unroll
    for (int o = 1; o < 64; o <<= 1) {
        int u = __shfl_up(incl, o);
        if (lane >= o) incl += u;
    }
    if (lane == 63) wtot[w8] = incl;
    __syncthreads();
    if (t == 0) {
        int r0 = 0;
#pragma unroll
        for (int k = 0; k < 8; k++) { int tmp = wtot[k]; wtot[k] = r0; r0 += tmp; }
    }
    __syncthreads();
    int run = incl - s + wtot[w8];

    int sub = blk & (SUBS - 1);
    int prefk[PER];
#pragma unroll
    for (int k = 0; k < PER; k++) {
        int i = beg + k;
        if (i < NBUCK) {
            prefk[k] = run;
            int c = cnt[i];
            if (c > 0) {
                int gb = atomicAdd(&gcur[i * SUBS + sub], c);   // relative cursor
                delta[i] = (i * BUCKCAP + sub * SUBCAP + gb) - run;
            }
            run += c;
        }
    }
    __syncthreads();
#pragma unroll
    for (int k = 0; k < PER; k++) { int i = beg + k; if (i < NBUCK) cnt[i] = prefk[k]; }
    __syncthreads();

#pragma unroll
    for (int q = 0; q < 8; q++) {
        if (bkt[q] >= 0) {
            int b = bkt[q];
            int pos = atomicAdd(&cnt[b], 1);
            sval[pos] = pay[q];
            sbkt[pos] = (unsigned short)b;
        }
    }
    __syncthreads();
    for (int i = t; i < n; i += 512)
        pairs[delta[sbkt[i]] + i] = sval[i];
}

// ============ proj GEMM (fp32 VALU, 256 thr, r2-proven) ============
struct GemmJob {
    const float* A1;
    const float* B1;
    const float* bias; unsigned short* Cbf;
    int lda1, K1, M;
};

__global__ void gemm_dual_kernel(GemmJob j0, GemmJob j1, int nb0) {
    __shared__ float sA[BK][BM];
    __shared__ float sB[BK][H];
    bool first = (int)blockIdx.x < nb0;
    GemmJob j = first ? j0 : j1;
    int bm = (first ? blockIdx.x : blockIdx.x - nb0) * BM;
    int tid = threadIdx.x;
    int am = tid >> 1;
    int ak = (tid & 1) * 4;
    int bk = tid >> 5;
    int bn = (tid & 31) * 4;
    int ty = tid >> 4;
    int tx = tid & 15;
    float acc[8][8] = {};
    for (int k0 = 0; k0 < j.K1; k0 += BK) {
        int gm = bm + am; if (gm >= j.M) gm = j.M - 1;
        float4 av = *(const float4*)&j.A1[(size_t)gm * j.lda1 + k0 + ak];
        float4 bv = *(const float4*)&j.B1[(size_t)(k0 + bk) * H + bn];
        __syncthreads();
        sA[ak + 0][am] = av.x; sA[ak + 1][am] = av.y;
        sA[ak + 2][am] = av.z; sA[ak + 3][am] = av.w;
        *(float4*)&sB[bk][bn] = bv;
        __syncthreads();
#pragma unroll
        for (int k = 0; k < BK; k++) {
            float a[8], bb[8];
            *(float4*)&a[0] = *(const float4*)&sA[k][ty * 8];
            *(float4*)&a[4] = *(const float4*)&sA[k][ty * 8 + 4];
            *(float4*)&bb[0] = *(const float4*)&sB[k][tx * 4];
            *(float4*)&bb[4] = *(const float4*)&sB[k][64 + tx * 4];
#pragma unroll
            for (int i = 0; i < 8; i++)
#pragma unroll
                for (int jj = 0; jj < 8; jj++)
                    acc[i][jj] += a[i] * bb[jj];
        }
    }
    float bcol[8];
    *(float4*)&bcol[0] = *(const float4*)&j.bias[tx * 4];
    *(float4*)&bcol[4] = *(const float4*)&j.bias[64 + tx * 4];
#pragma unroll
    for (int i = 0; i < 8; i++) {
        int gr = bm + ty * 8 + i;
        if (gr < j.M) {
#pragma unroll
            for (int q = 0; q < 8; q++) {
                float v = acc[i][q] + bcol[q];
                int gc = (q < 4) ? (tx * 4 + q) : (64 + tx * 4 + q - 4);
                j.Cbf[(size_t)gr * H + gc] = f2bf(v);
            }
        }
    }
}

// ============ shared gather body (reads soff/ssrc from LDS) ============
#define ACC8(a0, a1, v) \
    a0.x += bf2f_lo((v).x); a0.y += bf2f_hi((v).x); \
    a0.z += bf2f_lo((v).y); a0.w += bf2f_hi((v).y); \
    a1.x += bf2f_lo((v).z); a1.y += bf2f_hi((v).z); \
    a1.z += bf2f_lo((v).w); a1.w += bf2f_hi((v).w);

__device__ inline void gather_body(
        int t, int b, const int* soff, const unsigned short* ssrc,
        const unsigned short* __restrict__ xbf, unsigned short* __restrict__ aggn) {
    int wv = t >> 6, lane = t & 63;
    int g = lane >> 4;          // edge slot 0..3
    int q = lane & 15;          // uint4 index within row (16 B granule)
    int rowbase = (b < RELSPLIT_B) ? 0 : NPAT;
    int seglim  = (b < RELSPLIT_B) ? NCON : SEGN;
    const uint4* xw4 = (const uint4*)xbf;   // 16 x uint4 per row
    for (int i = 0; i < 8; i++) {
        int d = wv * 8 + i;
        int seg = b * 64 + d;
        if (seg >= seglim) continue;
        int beg = soff[d], end = soff[d + 1];
        float4 aA0 = {0.f, 0.f, 0.f, 0.f}, aA1 = {0.f, 0.f, 0.f, 0.f};
        float4 aB0 = {0.f, 0.f, 0.f, 0.f}, aB1 = {0.f, 0.f, 0.f, 0.f};
        int j = beg;
        for (; j + 7 < end; j += 8) {  // 8 edges via 2 independent uint4/lane
            int sA = ssrc[j + g];
            int sB = ssrc[j + 4 + g];
            uint4 vA = xw4[(size_t)(rowbase + sA) * 16 + q];
            uint4 vB = xw4[(size_t)(rowbase + sB) * 16 + q];
            ACC8(aA0, aA1, vA);
            ACC8(aB0, aB1, vB);
        }
        for (; j < end; j += 4) {      // tail: masked rounds of up to 4 edges
            if (g < end - j) {
                int s0 = ssrc[j + g];
                uint4 v = xw4[(size_t)(rowbase + s0) * 16 + q];
                ACC8(aA0, aA1, v);
            }
        }
        aA0.x += aB0.x; aA0.y += aB0.y; aA0.z += aB0.z; aA0.w += aB0.w;
        aA1.x += aB1.x; aA1.y += aB1.y; aA1.z += aB1.z; aA1.w += aB1.w;
        float r0 = aA0.x, r1 = aA0.y, r2 = aA0.z, r3 = aA0.w;
        float r4 = aA1.x, r5 = aA1.y, r6 = aA1.z, r7 = aA1.w;
        // reduce across the 4 edge-slots (lane bits 4 and 5)
        r0 += __shfl_xor(r0, 16); r1 += __shfl_xor(r1, 16);
        r2 += __shfl_xor(r2, 16); r3 += __shfl_xor(r3, 16);
        r4 += __shfl_xor(r4, 16); r5 += __shfl_xor(r5, 16);
        r6 += __shfl_xor(r6, 16); r7 += __shfl_xor(r7, 16);
        r0 += __shfl_xor(r0, 32); r1 += __shfl_xor(r1, 32);
        r2 += __shfl_xor(r2, 32); r3 += __shfl_xor(r3, 32);
        r4 += __shfl_xor(r4, 32); r5 += __shfl_xor(r5, 32);
        r6 += __shfl_xor(r6, 32); r7 += __shfl_xor(r7, 32);
        if (g == 0) {
            float inv = 1.0f / (float)max(end - beg, 1);
            uint4 o;
            o.x = (unsigned)f2bf(r0 * inv) | ((unsigned)f2bf(r1 * inv) << 16);
            o.y = (unsigned)f2bf(r2 * inv) | ((unsigned)f2bf(r3 * inv) << 16);
            o.z = (unsigned)f2bf(r4 * inv) | ((unsigned)f2bf(r5 * inv) << 16);
            o.w = (unsigned)f2bf(r6 * inv) | ((unsigned)f2bf(r7 * inv) << 16);
            *(uint4*)&aggn[(size_t)seg * H + 8 * q] = o;  // zero-deg segs write 0 (required)
        }
    }
}

// ============ layer-0: build CSR in LDS, dump for l1, gather from LDS ============
__global__ __launch_bounds__(512) void gather_build_kernel(
        const unsigned short* __restrict__ xbf,
        unsigned* __restrict__ pairs, const int* __restrict__ gcur,
        int* __restrict__ soffg, unsigned short* __restrict__ aggn) {
    __shared__ int cnt64[64];
    __shared__ int soff[65];
    __shared__ int scur[64];
    __shared__ unsigned short ssrc[CAP];
    int t = threadIdx.x, b = blockIdx.x;
    if (t < 64) cnt64[t] = 0;
    __syncthreads();
    // pass A: count per-seg degree over the 16 sub-regions
    for (int s = 0; s < SUBS; s++) {
        int rbase = b * BUCKCAP + s * SUBCAP;
        int rcnt = gcur[b * SUBS + s];
        for (int i = t; i < rcnt; i += 512)
            atomicAdd(&cnt64[pairs[rbase + i] >> 16], 1);
    }
    __syncthreads();
    if (t < 64) {  // wave 0: exclusive scan
        int v = cnt64[t];
        int s = v;
#pragma unroll
        for (int o = 1; o < 64; o <<= 1) {
            int u = __shfl_up(s, o);
            if (t >= o) s += u;
        }
        soff[t + 1] = s;
        if (t == 0) soff[0] = 0;
        scur[t] = s - v;
    }
    __syncthreads();
    // pass B: place srcs per-dst-contiguous
    for (int s = 0; s < SUBS; s++) {
        int rbase = b * BUCKCAP + s * SUBCAP;
        int rcnt = gcur[b * SUBS + s];
        for (int i = t; i < rcnt; i += 512) {
            unsigned p = pairs[rbase + i];
            int pos = atomicAdd(&scur[p >> 16], 1);
            ssrc[pos] = (unsigned short)(p & 0xFFFF);
        }
    }
    __syncthreads();
    // dump for layer 1 (fire-and-forget; overlaps the gather below)
    if (t < 65) soffg[b * 65 + t] = soff[t];
    int tot = soff[64];
    unsigned* sg = (unsigned*)(((unsigned short*)pairs) + (size_t)b * BUCKCAP * 2);
    const unsigned* sl = (const unsigned*)ssrc;
    for (int i = t; i < ((tot + 1) >> 1); i += 512) sg[i] = sl[i];
    // gather directly from the LDS csr just built
    gather_body(t, b, soff, ssrc, xbf, aggn);
}

// ============ layer-1 gather: load dumped CSR, then gather (r2-proven) ============
__global__ __launch_bounds__(512) void gather_kernel(
        const unsigned short* __restrict__ xbf,
        const unsigned short* __restrict__ ssrcg,
        const int* __restrict__ soffg,
        unsigned short* __restrict__ aggn) {
    __shared__ int soff[65];
    __shared__ unsigned short ssrc[CAP];
    int t = threadIdx.x, b = blockIdx.x;
    if (t < 65) soff[t] = soffg[b * 65 + t];
    __syncthreads();
    int tot = soff[64];
    const unsigned* sg = (const unsigned*)(ssrcg + (size_t)b * BUCKCAP * 2);
    unsigned* sl = (unsigned*)ssrc;
    for (int i = t; i < ((tot + 1) >> 1); i += 512) sl[i] = sg[i];
    __syncthreads();
    gather_body(t, b, soff, ssrc, xbf, aggn);
}

// ============ layer GEMM (bf16 MFMA, BK=64, r11): C = [A1|A2]@[BT1;BT2]+bias, relu
struct MJob {
    const unsigned short* A1;  // [M][H] bf16
    const unsigned short* A2;  // [M][H] bf16
    const unsigned short* BT1; // [2][128][64] bf16 slabs (k 0..127)
    const unsigned short* BT2; // [2][128][64] bf16 slabs (k 128..255)
    const float* bias;
    float* C;                  // fp32 or null
    unsigned short* Cbf;       // bf16 or null
    int M;
};

__global__ __launch_bounds__(256) void gemm_mfma_kernel(MJob j0, MJob j1, int nb0) {
    __shared__ unsigned short sA[128][72];   // [row][k] pad 64->72 (144B = 9x16)
    __shared__ unsigned short sBT[128][72];  // [col][k]
    bool first = (int)blockIdx.x < nb0;
    MJob J = first ? j0 : j1;
    int bm = (first ? (int)blockIdx.x : (int)blockIdx.x - nb0) * 128;
    int tid = threadIdx.x;
    int wv = tid >> 6, lane = tid & 63;
    int wr = wv >> 1, wc = wv & 1;
    int m16 = lane & 15, kg = lane >> 4;

    f32x4 acc[4][4];
#pragma unroll
    for (int a = 0; a < 4; a++)
#pragma unroll
        for (int c = 0; c < 4; c++) acc[a][c] = (f32x4){0.f, 0.f, 0.f, 0.f};

    int ar = tid >> 1, ah = (tid & 1) * 32;      // A: row, 32-short (64B) half
    int gmA = bm + ar; if (gmA >= J.M) gmA = J.M - 1;
    int bcol = tid >> 1, bko = (tid & 1) * 32;   // B: col, 32-short k-half

#pragma unroll
    for (int kt = 0; kt < 4; kt++) {
        int k0 = kt * 64;
        const unsigned short* asrc = (kt < 2)
            ? (J.A1 + (size_t)gmA * H + k0 + ah)
            : (J.A2 + (size_t)gmA * H + (k0 - 128) + ah);
        const uint4* a4 = (const uint4*)asrc;
        uint4 av0 = a4[0], av1 = a4[1], av2 = a4[2], av3 = a4[3];
        const unsigned short* slab = (kt < 2) ? (J.BT1 + kt * SLAB2)
                                              : (J.BT2 + (kt - 2) * SLAB2);
        const uint4* b4 = (const uint4*)(slab + bcol * 64 + bko);
        uint4 bv0 = b4[0], bv1 = b4[1], bv2 = b4[2], bv3 = b4[3];
        __syncthreads();
        { uint4* d4 = (uint4*)&sA[ar][ah];
          d4[0] = av0; d4[1] = av1; d4[2] = av2; d4[3] = av3; }
        { uint4* d4 = (uint4*)&sBT[bcol][bko];
          d4[0] = bv0; d4[1] = bv1; d4[2] = bv2; d4[3] = bv3; }
        __syncthreads();
#pragma unroll
        for (int kk = 0; kk < 2; kk++) {
            bf16x8 af[4], bfg[4];
#pragma unroll
            for (int mt = 0; mt < 4; mt++)
                af[mt] = *(bf16x8*)&sA[wr * 64 + mt * 16 + m16][kk * 32 + kg * 8];
#pragma unroll
            for (int nt = 0; nt < 4; nt++)
                bfg[nt] = *(bf16x8*)&sBT[wc * 64 + nt * 16 + m16][kk * 32 + kg * 8];
#pragma unroll
            for (int mt = 0; mt < 4; mt++)
#pragma unroll
                for (int nt = 0; nt < 4; nt++)
                    acc[mt][nt] = __builtin_amdgcn_mfma_f32_16x16x32_bf16(
                        af[mt], bfg[nt], acc[mt][nt], 0, 0, 0);
        }
    }
    float bv[4];
#pragma unroll
    for (int nt = 0; nt < 4; nt++) bv[nt] = J.bias[wc * 64 + nt * 16 + m16];
#pragma unroll
    for (int mt = 0; mt < 4; mt++) {
        int gr0 = bm + wr * 64 + mt * 16 + kg * 4;
#pragma unroll
        for (int r = 0; r < 4; r++) {
            int gr = gr0 + r;
            if (gr < J.M) {
#pragma unroll
                for (int nt = 0; nt < 4; nt++) {
                    int gc = wc * 64 + nt * 16 + m16;
                    float v = fmaxf(acc[mt][nt][r] + bv[nt], 0.f);
                    if (J.C)   J.C[(size_t)gr * H + gc] = v;
                    if (J.Cbf) J.Cbf[(size_t)gr * H + gc] = f2bf(v);
                }
            }
        }
    }
}

// ============ launch ============

static inline size_t align256(size_t x) { return (x + 255) & ~(size_t)255; }

extern "C" void kernel_launch(void* const* d_in, const int* in_sizes, int n_in,
                              void* d_out, int out_size, void* d_ws, size_t ws_size,
                              hipStream_t stream) {
    const float* x_patient = (const float*)d_in[0];
    const float* x_concept = (const float*)d_in[1];
    const float* W_p       = (const float*)d_in[2];
    const float* b_p       = (const float*)d_in[3];
    const float* W_c       = (const float*)d_in[4];
    const float* b_c       = (const float*)d_in[5];
    const float* W_root    = (const float*)d_in[6];
    const float* b_root    = (const float*)d_in[7];
    const float* W_rel     = (const float*)d_in[8];
    const int*   src_pc    = (const int*)d_in[9];
    const int*   dst_pc    = (const int*)d_in[10];
    const int*   src_cp    = (const int*)d_in[11];
    const int*   dst_cp    = (const int*)d_in[12];
    float* out = (float*)d_out;

    // every carve 256B-aligned (r8 lesson: unaligned carve -> misaligned uint4
    // accesses -> GPU fault)
    char* w = (char*)d_ws;
    unsigned short* xbf  = (unsigned short*)w; w += align256((size_t)NN * H * 2);
    unsigned short* aggn = (unsigned short*)w; w += align256((size_t)SEGN * H * 2);
    int* gcur = (int*)w;            w += align256((size_t)NBUCK * SUBS * 4);
    unsigned* pairs = (unsigned*)w; w += align256((size_t)NBUCK * BUCKCAP * 4);
    int* soffg = (int*)w;           w += align256((size_t)NBUCK * 65 * 4);
    unsigned short* prepW = (unsigned short*)w; w += align256((size_t)6 * MATW * 2);

    prep_weights_kernel<<<12 + ZBLKS, 256, 0, stream>>>(W_root, W_rel, prepW, gcur);
    binpack_kernel<<<NBB, 512, 0, stream>>>(dst_pc, src_pc, dst_cp, src_cp, gcur, pairs);
    const unsigned short* ssrcg = (const unsigned short*)pairs;  // l0 dumps here

    // projections -> xbf
    {
        GemmJob jp = { x_patient, W_p, b_p, xbf, 64, 64, NPAT };
        GemmJob jc = { x_concept, W_c, b_c, xbf + (size_t)NPAT * H, 128, 128, NCON };
        gemm_dual_kernel<<<PB_T + CB_T, 256, 0, stream>>>(jp, jc, PB_T);
    }

    for (int l = 0; l < 2; l++) {
        if (l == 0)
            gather_build_kernel<<<NBUCK, 512, 0, stream>>>(xbf, pairs, gcur, soffg, aggn);
        else
            gather_kernel<<<NBUCK, 512, 0, stream>>>(xbf, ssrcg, soffg, aggn);
        const unsigned short* BTroot = prepW + (size_t)(3 * l + 0) * MATW;
        const unsigned short* BTrel0 = prepW + (size_t)(3 * l + 1) * MATW;
        const unsigned short* BTrel1 = prepW + (size_t)(3 * l + 2) * MATW;
        const float* br = b_root + (size_t)l * H;
        float* cp = (l == 1) ? out : nullptr;
        float* cc = (l == 1) ? out + (size_t)NPAT * H : nullptr;
        unsigned short* bp = (l == 0) ? xbf : nullptr;                       // in-place ok
        unsigned short* bc = (l == 0) ? xbf + (size_t)NPAT * H : nullptr;
        MJob jp = { xbf, aggn + (size_t)NCON_AL * H, BTroot, BTrel1, br,
                    cp, bp, NPAT };
        MJob jc = { xbf + (size_t)NPAT * H, aggn, BTroot, BTrel0, br,
                    cc, bc, NCON };
        gemm_mfma_kernel<<<PB_T + CB_T, 256, 0, stream>>>(jp, jc, PB_T);
    }
}